// Round 2
// baseline (77.716 us; speedup 1.0000x reference)
//
#include <hip/hip_runtime.h>

#define NB     32
#define NKEYS  2048
#define D      512    // DK == DQ == DV == H
#define NCHUNK 32
#define RPC    (NKEYS / NCHUNK)   // 64 rows per chunk

__device__ __forceinline__ float wave_sum(float v) {
    #pragma unroll
    for (int o = 32; o > 0; o >>= 1) v += __shfl_xor(v, o);
    return v;
}
__device__ __forceinline__ float wave_max(float v) {
    #pragma unroll
    for (int o = 32; o > 0; o >>= 1) v = fmaxf(v, __shfl_xor(v, o));
    return v;
}

// blocks 0..511: wkh[dk] = Wk[dk,:]·Wh
// blocks 512..543: qdot[b] = sum_h((Q[b]@Wq)[h] + bk[h] + bq[h])·Wh[h] + bh
__global__ __launch_bounds__(256) void prep_kernel(const float* __restrict__ Wk,
        const float* __restrict__ Wq, const float* __restrict__ Wh,
        const float* __restrict__ Q, const float* __restrict__ bk,
        const float* __restrict__ bq, const float* __restrict__ bh,
        float* __restrict__ wkh, float* __restrict__ qdot) {
    int tid = threadIdx.x, lane = tid & 63, wv = tid >> 6;
    __shared__ float sred[4];
    if (blockIdx.x < D) {
        int dk = blockIdx.x;
        float s = 0.f;
        #pragma unroll
        for (int h = tid; h < D; h += 256) s = fmaf(Wk[dk * D + h], Wh[h], s);
        s = wave_sum(s);
        if (lane == 0) sred[wv] = s;
        __syncthreads();
        if (tid == 0) wkh[dk] = sred[0] + sred[1] + sred[2] + sred[3];
    } else {
        int b = blockIdx.x - D;
        __shared__ float sh_q[D];
        #pragma unroll
        for (int d = tid; d < D; d += 256) sh_q[d] = Q[b * D + d];
        __syncthreads();
        float acc = 0.f;
        #pragma unroll
        for (int hh = 0; hh < 2; ++hh) {
            int h = tid + hh * 256;
            float th = 0.f;
            for (int d = 0; d < D; ++d) th = fmaf(sh_q[d], Wq[d * D + h], th);
            acc = fmaf(th + bk[h] + bq[h], Wh[h], acc);
        }
        acc = wave_sum(acc);
        if (lane == 0) sred[wv] = acc;
        __syncthreads();
        if (tid == 0) qdot[b] = sred[0] + sred[1] + sred[2] + sred[3] + bh[0];
    }
}

// Per (b, chunk): energies for 64 K-rows, chunk-local softmax numerators,
// and the unnormalized weighted-V partial sum. Reads K and V once.
// grid: NB*NCHUNK = 1024 blocks x 256 threads
__global__ __launch_bounds__(256) void fused_kernel(const float* __restrict__ K,
        const float* __restrict__ V, const float* __restrict__ wkh,
        const float* __restrict__ qdot, float* __restrict__ p_out,
        float* __restrict__ mc_out, float* __restrict__ sc_out,
        float* __restrict__ y_out) {
    int chunk = blockIdx.x & (NCHUNK - 1);
    int b     = blockIdx.x >> 5;
    int tid = threadIdx.x, lane = tid & 63, wv = tid >> 6;
    long base = (long)b * NKEYS + chunk * RPC;
    __shared__ float sh[RPC];

    const float4* wr = (const float4*)wkh;
    float4 w0 = wr[lane], w1 = wr[lane + 64];
    float qd = qdot[b];

    // phase 1: energies (wave wv owns rows wv*16 .. wv*16+15)
    #pragma unroll 4
    for (int r = wv * 16; r < wv * 16 + 16; ++r) {
        const float4* kr = (const float4*)(K + (base + r) * D);
        float4 k0 = kr[lane], k1 = kr[lane + 64];
        float s = k0.x * w0.x + k0.y * w0.y + k0.z * w0.z + k0.w * w0.w
                + k1.x * w1.x + k1.y * w1.y + k1.z * w1.z + k1.w * w1.w;
        s = wave_sum(s);
        if (lane == 0) sh[r] = fmaxf(s + qd, 0.f);
    }
    __syncthreads();

    // phase 2 (wave 0 only): chunk max, p = exp(e - m_c), chunk sum
    if (wv == 0) {
        float e = sh[lane];
        float m = wave_max(e);
        float pv = expf(e - m);
        sh[lane] = pv;
        p_out[base + lane] = pv;
        float ssum = wave_sum(pv);
        if (lane == 0) { mc_out[b * NCHUNK + chunk] = m; sc_out[b * NCHUNK + chunk] = ssum; }
    }
    __syncthreads();

    // phase 3: y_c[v] = sum_r p[r] * V[row, v]   (thread owns v = 2tid, 2tid+1)
    const float2* vb = (const float2*)(V + base * D);
    float2 acc = {0.f, 0.f};
    #pragma unroll 4
    for (int r = 0; r < RPC; ++r) {
        float wt = sh[r];
        float2 vv = vb[r * (D / 2) + tid];
        acc.x = fmaf(wt, vv.x, acc.x);
        acc.y = fmaf(wt, vv.y, acc.y);
    }
    ((float2*)(y_out + ((long)(b * NCHUNK + chunk)) * D))[tid] = acc;
}

// Per batch: combine chunk stats, write normalized weights and output.
// grid: NB blocks x 256 threads
__global__ __launch_bounds__(256) void finalize_kernel(const float* __restrict__ p,
        const float* __restrict__ mc, const float* __restrict__ sc,
        const float* __restrict__ y, float* __restrict__ out,
        float* __restrict__ wout) {
    int b = blockIdx.x, tid = threadIdx.x;
    __shared__ float sh_f[NCHUNK];
    if (tid < NCHUNK) {
        float m_c = mc[b * NCHUNK + tid];
        float s_c = sc[b * NCHUNK + tid];
        float m = m_c;
        #pragma unroll
        for (int o = 16; o > 0; o >>= 1) m = fmaxf(m, __shfl_xor(m, o));
        float ex = expf(m_c - m);
        float S = s_c * ex;
        #pragma unroll
        for (int o = 1; o < 32; o <<= 1) S += __shfl_xor(S, o);
        sh_f[tid] = ex / S;
    }
    __syncthreads();

    const float* pb = p + b * NKEYS;
    float* wb = wout + b * NKEYS;
    #pragma unroll
    for (int i = 0; i < 8; ++i) {
        int n = tid + i * 256;
        wb[n] = pb[n] * sh_f[n >> 6];
    }

    float2 acc = {0.f, 0.f};
    const float2* yb = (const float2*)(y + (long)b * NCHUNK * D);
    #pragma unroll
    for (int c = 0; c < NCHUNK; ++c) {
        float f = sh_f[c];
        float2 vv = yb[c * (D / 2) + tid];
        acc.x = fmaf(f, vv.x, acc.x);
        acc.y = fmaf(f, vv.y, acc.y);
    }
    ((float2*)(out + b * D))[tid] = acc;
}

extern "C" void kernel_launch(void* const* d_in, const int* in_sizes, int n_in,
                              void* d_out, int out_size, void* d_ws, size_t ws_size,
                              hipStream_t stream) {
    const float* Q  = (const float*)d_in[0];
    const float* K  = (const float*)d_in[1];
    const float* V  = (const float*)d_in[2];
    const float* Wk = (const float*)d_in[3];
    const float* bk = (const float*)d_in[4];
    const float* Wq = (const float*)d_in[5];
    const float* bq = (const float*)d_in[6];
    const float* Wh = (const float*)d_in[7];
    const float* bh = (const float*)d_in[8];

    float* out  = (float*)d_out;              // [32, 512]
    float* wout = out + NB * D;               // [32, 2048]

    float* ws   = (float*)d_ws;
    float* wkh  = ws;                          // 512
    float* qdot = ws + 512;                    // 32
    float* pbuf = ws + 1024;                   // 65536
    float* mc   = pbuf + NB * NKEYS;           // 1024
    float* sc   = mc + NB * NCHUNK;            // 1024
    float* ybuf = sc + NB * NCHUNK;            // 524288

    prep_kernel<<<D + NB, 256, 0, stream>>>(Wk, Wq, Wh, Q, bk, bq, bh, wkh, qdot);
    fused_kernel<<<NB * NCHUNK, 256, 0, stream>>>(K, V, wkh, qdot, pbuf, mc, sc, ybuf);
    finalize_kernel<<<NB, 256, 0, stream>>>(pbuf, mc, sc, ybuf, out, wout);
}

// Round 3
// 67.140 us; speedup vs baseline: 1.1575x; 1.1575x over previous
//
#include <hip/hip_runtime.h>

#define NB    32
#define NKEYS 2048
#define D     512
#define RPW   8                    // rows per wave
#define SUBS  (NKEYS / RPW)        // 256 sub-chunks per batch
#define NWAVE (NB * SUBS)          // 8192 waves

__device__ __forceinline__ float wave_sum(float v) {
    #pragma unroll
    for (int o = 32; o > 0; o >>= 1) v += __shfl_xor(v, o);
    return v;
}

// blocks 0..511: wkh[dk] = Wk[dk,:]·Wh ; wqh[dk] = Wq[dk,:]·Wh   (rows coalesced)
// block 512:     cbias = sum_h (bk+bq)·Wh + bh
__global__ __launch_bounds__(256) void prep_kernel(const float* __restrict__ Wk,
        const float* __restrict__ Wq, const float* __restrict__ Wh,
        const float* __restrict__ bk, const float* __restrict__ bq,
        const float* __restrict__ bh,
        float* __restrict__ wkh, float* __restrict__ wqh, float* __restrict__ cbias) {
    int tid = threadIdx.x, lane = tid & 63, wv = tid >> 6;
    __shared__ float sred[8];
    if (blockIdx.x < D) {
        int dk = blockIdx.x;
        float sk = 0.f, sq = 0.f;
        #pragma unroll
        for (int h = tid; h < D; h += 256) {
            float wh = Wh[h];
            sk = fmaf(Wk[dk * D + h], wh, sk);
            sq = fmaf(Wq[dk * D + h], wh, sq);
        }
        sk = wave_sum(sk); sq = wave_sum(sq);
        if (lane == 0) { sred[wv] = sk; sred[wv + 4] = sq; }
        __syncthreads();
        if (tid == 0) wkh[dk] = sred[0] + sred[1] + sred[2] + sred[3];
        if (tid == 1) wqh[dk] = sred[4] + sred[5] + sred[6] + sred[7];
    } else {
        float s = 0.f;
        #pragma unroll
        for (int h = tid; h < D; h += 256) s = fmaf(bk[h] + bq[h], Wh[h], s);
        s = wave_sum(s);
        if (lane == 0) sred[wv] = s;
        __syncthreads();
        if (tid == 0) cbias[0] = sred[0] + sred[1] + sred[2] + sred[3] + bh[0];
    }
}

// One wave per 8 K-rows: energies -> p = exp(relu(e)) -> weighted-V partial.
// No LDS, no barriers. grid: NWAVE/4 = 2048 blocks x 256 threads.
__global__ __launch_bounds__(256, 4) void mega_kernel(const float* __restrict__ K,
        const float* __restrict__ V, const float* __restrict__ Q,
        const float* __restrict__ wkh, const float* __restrict__ wqh,
        const float* __restrict__ cbias,
        float* __restrict__ p_out, float* __restrict__ partial) {
    int tid = threadIdx.x, lane = tid & 63, wv = tid >> 6;
    int gw = blockIdx.x * 4 + wv;            // 0 .. 8191
    int b  = gw >> 8;
    long rowbase = (long)b * NKEYS + (gw & (SUBS - 1)) * RPW;

    const float4* wk4 = (const float4*)wkh;
    float4 wa = wk4[lane], wb = wk4[lane + 64];

    // qdot[b] recomputed per wave (L2-hot 4KB reads)
    const float4* q4  = (const float4*)(Q + b * D);
    const float4* wq4 = (const float4*)wqh;
    float4 qa = q4[lane], qb = q4[lane + 64];
    float4 xa = wq4[lane], xb = wq4[lane + 64];
    float qd = qa.x * xa.x + qa.y * xa.y + qa.z * xa.z + qa.w * xa.w
             + qb.x * xb.x + qb.y * xb.y + qb.z * xb.z + qb.w * xb.w;
    qd = wave_sum(qd) + cbias[0];

    // energies + p for 8 rows (butterfly sum -> every lane has p[r])
    float p[RPW];
    #pragma unroll
    for (int r = 0; r < RPW; ++r) {
        const float4* kr = (const float4*)(K + (rowbase + r) * D);
        float4 ka = kr[lane], kb = kr[lane + 64];
        float s = ka.x * wa.x + ka.y * wa.y + ka.z * wa.z + ka.w * wa.w
                + kb.x * wb.x + kb.y * wb.y + kb.z * wb.z + kb.w * wb.w;
        s = wave_sum(s);
        p[r] = expf(fmaxf(s + qd, 0.f));   // no max-shift: relu bounds e
    }

    // store the 8 unnormalized weights (lane r writes p[r])
    float pst = p[0];
    #pragma unroll
    for (int r = 1; r < RPW; ++r) if (lane == r) pst = p[r];
    if (lane < RPW) p_out[rowbase + lane] = pst;

    // weighted-V partial for the same 8 rows
    float4 ya = {0.f, 0.f, 0.f, 0.f}, yb = {0.f, 0.f, 0.f, 0.f};
    #pragma unroll
    for (int r = 0; r < RPW; ++r) {
        const float4* vr = (const float4*)(V + (rowbase + r) * D);
        float4 va = vr[lane], vb4 = vr[lane + 64];
        float w = p[r];
        ya.x = fmaf(w, va.x, ya.x);  ya.y = fmaf(w, va.y, ya.y);
        ya.z = fmaf(w, va.z, ya.z);  ya.w = fmaf(w, va.w, ya.w);
        yb.x = fmaf(w, vb4.x, yb.x); yb.y = fmaf(w, vb4.y, yb.y);
        yb.z = fmaf(w, vb4.z, yb.z); yb.w = fmaf(w, vb4.w, yb.w);
    }
    float4* po = (float4*)(partial + (long)gw * D);
    po[lane]      = ya;
    po[lane + 64] = yb;
}

// grid: 64 blocks (b, half) x 256 threads.
// Sum_p -> inv; write normalized weights; combine 256 partials -> out.
__global__ __launch_bounds__(256) void finalize_kernel(const float* __restrict__ p,
        const float* __restrict__ partial, float* __restrict__ out,
        float* __restrict__ wout) {
    int b = blockIdx.x >> 1, half = blockIdx.x & 1;
    int tid = threadIdx.x, lane = tid & 63, wv = tid >> 6;

    const float4* p4 = (const float4*)(p + b * NKEYS);
    float s = 0.f;
    #pragma unroll
    for (int i = 0; i < 2; ++i) {
        float4 v = p4[tid + i * 256];
        s += v.x + v.y + v.z + v.w;
    }
    s = wave_sum(s);
    __shared__ float sred[4];
    if (lane == 0) sred[wv] = s;
    __syncthreads();
    float inv = 1.f / (sred[0] + sred[1] + sred[2] + sred[3]);

    // normalized weights: this block writes 1024 of 2048
    const float* pb = p + b * NKEYS + half * 1024;
    float* wb = wout + b * NKEYS + half * 1024;
    #pragma unroll
    for (int i = 0; i < 4; ++i) wb[tid + i * 256] = pb[tid + i * 256] * inv;

    // output: this block owns 256 of 512 v-floats
    int v = half * 256 + tid;
    const float* pp = partial + (long)b * SUBS * D + v;
    float acc = 0.f;
    #pragma unroll 8
    for (int sc = 0; sc < SUBS; ++sc) acc += pp[(long)sc * D];
    out[b * D + v] = acc * inv;
}

extern "C" void kernel_launch(void* const* d_in, const int* in_sizes, int n_in,
                              void* d_out, int out_size, void* d_ws, size_t ws_size,
                              hipStream_t stream) {
    const float* Q  = (const float*)d_in[0];
    const float* K  = (const float*)d_in[1];
    const float* V  = (const float*)d_in[2];
    const float* Wk = (const float*)d_in[3];
    const float* bk = (const float*)d_in[4];
    const float* Wq = (const float*)d_in[5];
    const float* bq = (const float*)d_in[6];
    const float* Wh = (const float*)d_in[7];
    const float* bh = (const float*)d_in[8];

    float* out  = (float*)d_out;               // [32, 512]
    float* wout = out + NB * D;                // [32, 2048]

    float* ws      = (float*)d_ws;
    float* wkh     = ws;                       // 512
    float* wqh     = ws + 512;                 // 512
    float* cbias   = ws + 1024;                // 1 (padded)
    float* pbuf    = ws + 1088;                // 65536
    float* partial = pbuf + NB * NKEYS;        // 8192*512 = 4194304

    prep_kernel<<<D + 1, 256, 0, stream>>>(Wk, Wq, Wh, bk, bq, bh, wkh, wqh, cbias);
    mega_kernel<<<NWAVE / 4, 256, 0, stream>>>(K, V, Q, wkh, wqh, cbias, pbuf, partial);
    finalize_kernel<<<NB * 2, 256, 0, stream>>>(pbuf, partial, out, wout);
}

// Round 4
// 57.908 us; speedup vs baseline: 1.3421x; 1.1594x over previous
//
#include <hip/hip_runtime.h>

#define NB     32
#define NKEYS  2048
#define D      512
#define NCHUNK 64
#define RPC    (NKEYS / NCHUNK)    // 32 rows per chunk

__device__ __forceinline__ float wave_sum(float v) {
    #pragma unroll
    for (int o = 32; o > 0; o >>= 1) v += __shfl_xor(v, o);
    return v;
}

// blocks 0..511: wkh[dk] = Wk[dk,:]·Wh ; wqh[dk] = Wq[dk,:]·Wh
// block 512:     cbias = (bk+bq)·Wh + bh
__global__ __launch_bounds__(256) void prep_kernel(const float* __restrict__ Wk,
        const float* __restrict__ Wq, const float* __restrict__ Wh,
        const float* __restrict__ bk, const float* __restrict__ bq,
        const float* __restrict__ bh,
        float* __restrict__ wkh, float* __restrict__ wqh, float* __restrict__ cbias) {
    int tid = threadIdx.x, lane = tid & 63, wv = tid >> 6;
    __shared__ float sred[8];
    if (blockIdx.x < D) {
        int dk = blockIdx.x;
        float sk = 0.f, sq = 0.f;
        #pragma unroll
        for (int h = tid; h < D; h += 256) {
            float wh = Wh[h];
            sk = fmaf(Wk[dk * D + h], wh, sk);
            sq = fmaf(Wq[dk * D + h], wh, sq);
        }
        sk = wave_sum(sk); sq = wave_sum(sq);
        if (lane == 0) { sred[wv] = sk; sred[wv + 4] = sq; }
        __syncthreads();
        if (tid == 0) wkh[dk] = sred[0] + sred[1] + sred[2] + sred[3];
        if (tid == 1) wqh[dk] = sred[4] + sred[5] + sred[6] + sred[7];
    } else {
        float s = 0.f;
        #pragma unroll
        for (int h = tid; h < D; h += 256) s = fmaf(bk[h] + bq[h], Wh[h], s);
        s = wave_sum(s);
        if (lane == 0) sred[wv] = s;
        __syncthreads();
        if (tid == 0) cbias[0] = sred[0] + sred[1] + sred[2] + sred[3] + bh[0];
    }
}

// qdot[b] = Q[b,:]·wqh + cbias   — one wave per batch
__global__ void qdot_kernel(const float* __restrict__ Q, const float* __restrict__ wqh,
                            const float* __restrict__ cbias, float* __restrict__ qdot) {
    int b = blockIdx.x, lane = threadIdx.x;
    const float4* q4 = (const float4*)(Q + b * D);
    const float4* w4 = (const float4*)wqh;
    float4 qa = q4[lane], qb = q4[lane + 64];
    float4 wa = w4[lane], wb = w4[lane + 64];
    float s = qa.x * wa.x + qa.y * wa.y + qa.z * wa.z + qa.w * wa.w
            + qb.x * wb.x + qb.y * wb.y + qb.z * wb.z + qb.w * wb.w;
    s = wave_sum(s);
    if (lane == 0) qdot[b] = s + cbias[0];
}

// p[b,n] = exp(relu(K[b,n,:]·wkh + qdot[b]))   — one wave per K-row
// grid: (NB*NKEYS)/4 = 16384 blocks x 256 threads. Pure K stream.
__global__ __launch_bounds__(256) void energy_kernel(const float* __restrict__ K,
        const float* __restrict__ wkh, const float* __restrict__ qdot,
        float* __restrict__ p) {
    int tid  = threadIdx.x;
    int lane = tid & 63, wv = tid >> 6;
    long row = (long)blockIdx.x * 4 + wv;           // 0 .. 65535
    int b = (int)(row >> 11);
    const float4* kr = (const float4*)(K + row * D);
    const float4* wr = (const float4*)wkh;
    float4 k0 = kr[lane],      w0 = wr[lane];
    float4 k1 = kr[lane + 64], w1 = wr[lane + 64];
    float s = k0.x * w0.x + k0.y * w0.y + k0.z * w0.z + k0.w * w0.w
            + k1.x * w1.x + k1.y * w1.y + k1.z * w1.z + k1.w * w1.w;
    s = wave_sum(s);
    // relu bounds energies (O(±5)); exp without max-shift is safe in fp32 and
    // cancels identically after normalization.
    if (lane == 0) p[row] = expf(fmaxf(s + qdot[b], 0.f));
}

// partial[b,chunk,v] = sum_{r in chunk} p[b,n0+r] * V[b,n0+r,v]
// p values read as uniform (scalar) loads — no LDS, no barrier. Pure V stream.
// grid: NB*NCHUNK = 2048 blocks x 256 threads; thread owns v = 2t, 2t+1.
__global__ __launch_bounds__(256) void weightedv_kernel(const float* __restrict__ V,
        const float* __restrict__ p, float* __restrict__ partial) {
    int chunk = blockIdx.x & (NCHUNK - 1);
    int b     = blockIdx.x >> 6;
    int tid   = threadIdx.x;
    int n0    = chunk * RPC;
    const float* pb = p + b * NKEYS + n0;
    float pw[RPC];
    #pragma unroll
    for (int r = 0; r < RPC; ++r) pw[r] = pb[r];    // uniform -> s_load
    const float2* vb = (const float2*)(V + ((long)b * NKEYS + n0) * D);
    float2 acc = {0.f, 0.f};
    #pragma unroll 8
    for (int r = 0; r < RPC; ++r) {
        float2 vv = vb[r * (D / 2) + tid];
        acc.x = fmaf(pw[r], vv.x, acc.x);
        acc.y = fmaf(pw[r], vv.y, acc.y);
    }
    ((float2*)(partial + (long)blockIdx.x * D))[tid] = acc;
}

// Per batch: S = sum p; wout = p/S; out = (sum_c partial_c)/S.
// grid: NB blocks x 256 threads
__global__ __launch_bounds__(256) void finalize_kernel(const float* __restrict__ p,
        const float* __restrict__ partial, float* __restrict__ out,
        float* __restrict__ wout) {
    int b = blockIdx.x, tid = threadIdx.x;
    int lane = tid & 63, wv = tid >> 6;

    const float4* p4 = (const float4*)(p + b * NKEYS);
    float4 v0 = p4[tid], v1 = p4[tid + 256];
    float s = v0.x + v0.y + v0.z + v0.w + v1.x + v1.y + v1.z + v1.w;
    s = wave_sum(s);
    __shared__ float sred[4];
    if (lane == 0) sred[wv] = s;
    __syncthreads();
    float inv = 1.f / (sred[0] + sred[1] + sred[2] + sred[3]);

    float4* wo = (float4*)(wout + b * NKEYS);
    v0.x *= inv; v0.y *= inv; v0.z *= inv; v0.w *= inv;
    v1.x *= inv; v1.y *= inv; v1.z *= inv; v1.w *= inv;
    wo[tid] = v0;
    wo[tid + 256] = v1;

    const float2* yb = (const float2*)(partial + (long)b * NCHUNK * D);
    float2 acc = {0.f, 0.f};
    #pragma unroll
    for (int c = 0; c < NCHUNK; ++c) {
        float2 vv = yb[c * (D / 2) + tid];
        acc.x += vv.x;
        acc.y += vv.y;
    }
    acc.x *= inv; acc.y *= inv;
    ((float2*)(out + b * D))[tid] = acc;
}

extern "C" void kernel_launch(void* const* d_in, const int* in_sizes, int n_in,
                              void* d_out, int out_size, void* d_ws, size_t ws_size,
                              hipStream_t stream) {
    const float* Q  = (const float*)d_in[0];
    const float* K  = (const float*)d_in[1];
    const float* V  = (const float*)d_in[2];
    const float* Wk = (const float*)d_in[3];
    const float* bk = (const float*)d_in[4];
    const float* Wq = (const float*)d_in[5];
    const float* bq = (const float*)d_in[6];
    const float* Wh = (const float*)d_in[7];
    const float* bh = (const float*)d_in[8];

    float* out  = (float*)d_out;               // [32, 512]
    float* wout = out + NB * D;                // [32, 2048]

    float* ws      = (float*)d_ws;
    float* wkh     = ws;                       // 512
    float* wqh     = ws + 512;                 // 512
    float* cbias   = ws + 1024;                // 1 (padded to 64)
    float* qdot    = ws + 1088;                // 32 (padded to 64)
    float* pbuf    = ws + 1152;                // 65536
    float* partial = pbuf + NB * NKEYS;        // 32*64*512 = 1048576

    prep_kernel<<<D + 1, 256, 0, stream>>>(Wk, Wq, Wh, bk, bq, bh, wkh, wqh, cbias);
    qdot_kernel<<<NB, 64, 0, stream>>>(Q, wqh, cbias, qdot);
    energy_kernel<<<(NB * NKEYS) / 4, 256, 0, stream>>>(K, wkh, qdot, pbuf);
    weightedv_kernel<<<NB * NCHUNK, 256, 0, stream>>>(V, pbuf, partial);
    finalize_kernel<<<NB, 256, 0, stream>>>(pbuf, partial, out, wout);
}